// Round 4
// baseline (1005.167 us; speedup 1.0000x reference)
//
#include <hip/hip_runtime.h>
#include <math.h>

#define NEG_SLOPE 0.2f
#define EPS_DEN 1e-16f

__device__ __forceinline__ float leaky(float v) { return v > 0.f ? v : NEG_SLOPE * v; }

typedef __attribute__((ext_vector_type(8))) short bf16x8;
typedef __attribute__((ext_vector_type(4))) float f32x4;

__device__ __forceinline__ unsigned bf16rne(float f) {
    unsigned u = __float_as_uint(f);
    return (u + 0x7FFFu + ((u >> 16) & 1u)) >> 16;
}
__device__ __forceinline__ unsigned pack2(float a, float b) {
    return bf16rne(a) | (bf16rne(b) << 16);
}

// ---------- GEMM1 (MFMA): h1[N,64] = x[N,512] @ W1[512,64] ----------
__global__ __launch_bounds__(256) void gemm1_mfma(
    const float* __restrict__ x, const float* __restrict__ W1,
    float* __restrict__ h1, int N)
{
    __shared__ __align__(16) unsigned short As[128 * 40];
    __shared__ __align__(16) unsigned short Bs[64 * 40];

    const int t = threadIdx.x;
    const int w = t >> 6;
    const int lane = t & 63;
    const int m16 = lane & 15;
    const int quad = lane >> 4;
    const int rowBase = blockIdx.x * 128;

    f32x4 acc[2][4];
#pragma unroll
    for (int i = 0; i < 2; ++i)
#pragma unroll
        for (int j = 0; j < 4; ++j) acc[i][j] = (f32x4){0.f, 0.f, 0.f, 0.f};

    const float4* x4 = (const float4*)x;

#pragma unroll 1
    for (int chunk = 0; chunk < 16; ++chunk) {
        const int k0 = chunk * 32;
#pragma unroll
        for (int r = 0; r < 4; ++r) {
            int e = t + r * 256;
            int row = e >> 3;
            int kg = e & 7;
            int grow = rowBase + row;
            float4 v = make_float4(0.f, 0.f, 0.f, 0.f);
            if (grow < N) v = x4[(size_t)grow * 128 + (k0 >> 2) + kg];
            uint2 pk = make_uint2(pack2(v.x, v.y), pack2(v.z, v.w));
            *(uint2*)&As[row * 40 + kg * 4] = pk;
        }
        {
            int c = lane;
            int jb = w * 8;
            float f[8];
#pragma unroll
            for (int j = 0; j < 8; ++j) f[j] = W1[(size_t)(k0 + jb + j) * 64 + c];
            uint4 pk;
            pk.x = pack2(f[0], f[1]); pk.y = pack2(f[2], f[3]);
            pk.z = pack2(f[4], f[5]); pk.w = pack2(f[6], f[7]);
            *(uint4*)&Bs[c * 40 + jb] = pk;
        }
        __syncthreads();
        bf16x8 a0 = *(const bf16x8*)&As[(w * 32 + m16) * 40 + quad * 8];
        bf16x8 a1 = *(const bf16x8*)&As[(w * 32 + 16 + m16) * 40 + quad * 8];
#pragma unroll
        for (int j = 0; j < 4; ++j) {
            bf16x8 b = *(const bf16x8*)&Bs[(j * 16 + m16) * 40 + quad * 8];
            acc[0][j] = __builtin_amdgcn_mfma_f32_16x16x32_bf16(a0, b, acc[0][j], 0, 0, 0);
            acc[1][j] = __builtin_amdgcn_mfma_f32_16x16x32_bf16(a1, b, acc[1][j], 0, 0, 0);
        }
        __syncthreads();
    }

#pragma unroll
    for (int i = 0; i < 2; ++i)
#pragma unroll
        for (int reg = 0; reg < 4; ++reg) {
            int r = rowBase + w * 32 + i * 16 + quad * 4 + reg;
            if (r < N) {
#pragma unroll
                for (int j = 0; j < 4; ++j)
                    h1[(size_t)r * 64 + j * 16 + m16] = acc[i][j][reg];
            }
        }
}

// ---------- attention dots for L1 ----------
__global__ __launch_bounds__(256) void att1_kernel(
    const float* __restrict__ h1, const float* __restrict__ att_src,
    const float* __restrict__ att_dst, float* __restrict__ a_src,
    float* __restrict__ a_dst, int N)
{
    int g = blockIdx.x * 256 + threadIdx.x;
    int row = g >> 3, h = g & 7;
    if (row >= N) return;
    const float* hp = h1 + (size_t)row * 64 + h * 8;
    float ps = 0.f, pd = 0.f;
#pragma unroll
    for (int c = 0; c < 8; ++c) {
        float v = hp[c];
        ps += v * att_src[h * 8 + c];
        pd += v * att_dst[h * 8 + c];
    }
    a_src[(size_t)row * 8 + h] = ps;
    a_dst[(size_t)row * 8 + h] = pd;
}

// ---------- CSR build ----------
__global__ __launch_bounds__(256) void deg_kernel(
    const int* __restrict__ ei, unsigned* __restrict__ deg, int E, int Etot)
{
    int idx = blockIdx.x * blockDim.x + threadIdx.x;
    if (idx >= Etot) return;
    int d = (idx < E) ? ei[E + idx] : (idx - E);
    atomicAdd(&deg[d], 1u);
}

__global__ __launch_bounds__(256) void scanA_kernel(
    const unsigned* __restrict__ deg, unsigned* __restrict__ loc,
    unsigned* __restrict__ bsum, int N)
{
    __shared__ unsigned sh[256];
    int i = blockIdx.x * 256 + threadIdx.x;
    unsigned v = (i < N) ? deg[i] : 0u;
    sh[threadIdx.x] = v;
    __syncthreads();
    for (int off = 1; off < 256; off <<= 1) {
        unsigned u = (threadIdx.x >= (unsigned)off) ? sh[threadIdx.x - off] : 0u;
        __syncthreads();
        sh[threadIdx.x] += u;
        __syncthreads();
    }
    if (i < N) loc[i] = sh[threadIdx.x] - v;
    if (threadIdx.x == 255) bsum[blockIdx.x] = sh[255];
}

__global__ __launch_bounds__(1024) void scanB_kernel(unsigned* __restrict__ bsum, int nb)
{
    __shared__ unsigned sh[1024];
    int t = threadIdx.x;
    unsigned carry = 0;
    for (int base = 0; base < nb; base += 1024) {
        int i = base + t;
        unsigned v = (i < nb) ? bsum[i] : 0u;
        sh[t] = v;
        __syncthreads();
        for (int off = 1; off < 1024; off <<= 1) {
            unsigned u = (t >= off) ? sh[t - off] : 0u;
            __syncthreads();
            sh[t] += u;
            __syncthreads();
        }
        unsigned incl = sh[t];
        unsigned tot  = sh[1023];
        __syncthreads();
        if (i < nb) bsum[i] = incl - v + carry;
        carry += tot;
        __syncthreads();
    }
}

__global__ __launch_bounds__(256) void scanC_kernel(
    const unsigned* __restrict__ loc, const unsigned* __restrict__ bsum,
    unsigned* __restrict__ rowstart, unsigned* __restrict__ cursor, int N, int Etot)
{
    int i = blockIdx.x * 256 + threadIdx.x;
    if (i >= N) return;
    unsigned r = loc[i] + bsum[blockIdx.x];
    rowstart[i] = r;
    cursor[i] = r;
    if (i == 0) rowstart[N] = (unsigned)Etot;
}

__global__ __launch_bounds__(256) void scatter_kernel(
    const int* __restrict__ ei, unsigned* __restrict__ cursor,
    int* __restrict__ csr_src, int E, int Etot)
{
    int idx = blockIdx.x * blockDim.x + threadIdx.x;
    if (idx >= Etot) return;
    int s, d;
    if (idx < E) { s = ei[idx]; d = ei[E + idx]; } else { s = d = idx - E; }
    unsigned pos = atomicAdd(&cursor[d], 1u);
    csr_src[pos] = s;
}

// ---------- L1 softmax scalars: thread per (dst, head) ----------
__global__ __launch_bounds__(256) void mden1_kernel(
    const unsigned* __restrict__ rowstart, const int* __restrict__ csr_src,
    const float* __restrict__ a_src, const float* __restrict__ a_dst,
    float* __restrict__ m1, float* __restrict__ den1, int N)
{
    int g = blockIdx.x * 256 + threadIdx.x;
    int dst = g >> 3, h = g & 7;
    if (dst >= N) return;
    float ad = a_dst[(size_t)dst * 8 + h];
    unsigned k0 = rowstart[dst], k1 = rowstart[dst + 1];
    float m = -INFINITY;
    for (unsigned k = k0; k < k1; ++k) {
        int s = csr_src[k];
        m = fmaxf(m, leaky(a_src[(size_t)s * 8 + h] + ad));
    }
    float den = 0.f;
    for (unsigned k = k0; k < k1; ++k) {
        int s = csr_src[k];
        den += expf(leaky(a_src[(size_t)s * 8 + h] + ad) - m);
    }
    m1[(size_t)dst * 8 + h] = m;
    den1[(size_t)dst * 8 + h] = den;
}

// ---------- L1 aggregate: wave per dst, plain weighted sum ----------
__global__ __launch_bounds__(256) void aggr1_kernel(
    const unsigned* __restrict__ rowstart, const int* __restrict__ csr_src,
    const float* __restrict__ a_src, const float* __restrict__ a_dst,
    const float* __restrict__ m1, const float* __restrict__ den1,
    const float* __restrict__ h1, const float* __restrict__ b1,
    float* __restrict__ h2, int N)
{
    int g = blockIdx.x * 4 + (threadIdx.x >> 6);
    int lane = threadIdx.x & 63;
    if (g >= N) return;
    int h = lane >> 3;
    float ad = a_dst[(size_t)g * 8 + h];
    float m  = m1[(size_t)g * 8 + h];
    unsigned k0 = rowstart[g], k1 = rowstart[g + 1];
    float acc = 0.f;
    for (unsigned k = k0; k < k1; ++k) {
        int s = csr_src[k];
        float p = expf(leaky(a_src[(size_t)s * 8 + h] + ad) - m);
        acc += p * h1[(size_t)s * 64 + lane];
    }
    float v = acc / (den1[(size_t)g * 8 + h] + EPS_DEN) + b1[lane];
    h2[(size_t)g * 64 + lane] = v > 0.f ? v : 0.f;
}

// ---------- GEMM2 + attention dots ----------
__global__ __launch_bounds__(256) void gemm2_kernel(
    const float* __restrict__ h2, const float* __restrict__ W2,
    const float* __restrict__ att_src2, const float* __restrict__ att_dst2,
    float* __restrict__ h3, float* __restrict__ a_src, float* __restrict__ a_dst, int N)
{
    __shared__ float Wl[64 * 40];
    int t = threadIdx.x;
    for (int i = t; i < 64 * 40; i += 256) Wl[i] = W2[i];
    __syncthreads();
    int lane = t & 63, wy = t >> 6;
    int row = blockIdx.x * 4 + wy;
    if (row >= N) return;
    float acc = 0.f;
    const float* hr = h2 + (size_t)row * 64;
    if (lane < 40) {
#pragma unroll 8
        for (int k = 0; k < 64; ++k) acc += hr[k] * Wl[k * 40 + lane];
        h3[(size_t)row * 40 + lane] = acc;
    }
    float ps = (lane < 40) ? acc * att_src2[lane] : 0.f;
    float pd = (lane < 40) ? acc * att_dst2[lane] : 0.f;
#pragma unroll
    for (int off = 32; off; off >>= 1) { ps += __shfl_down(ps, off); pd += __shfl_down(pd, off); }
    if (lane == 0) { a_src[row] = ps; a_dst[row] = pd; }
}

// ---------- L2 alpha: thread per dst, store unnormalized p per edge ----------
__global__ __launch_bounds__(256) void alpha2_kernel(
    const unsigned* __restrict__ rowstart, const int* __restrict__ csr_src,
    const float* __restrict__ a_src, const float* __restrict__ a_dst,
    float* __restrict__ alpha2, float* __restrict__ den2, int N)
{
    int g = blockIdx.x * 256 + threadIdx.x;
    if (g >= N) return;
    float ad = a_dst[g];
    unsigned k0 = rowstart[g], k1 = rowstart[g + 1];
    float m = -INFINITY;
    for (unsigned k = k0; k < k1; ++k)
        m = fmaxf(m, leaky(a_src[csr_src[k]] + ad));
    float den = 0.f;
    for (unsigned k = k0; k < k1; ++k) {
        float p = expf(leaky(a_src[csr_src[k]] + ad) - m);
        den += p;
        alpha2[k] = p;
    }
    den2[g] = den;
}

// ---------- L2 aggregate: wave per dst, fused bias+log_softmax ----------
__global__ __launch_bounds__(256) void aggr2_kernel(
    const unsigned* __restrict__ rowstart, const int* __restrict__ csr_src,
    const float* __restrict__ alpha2, const float* __restrict__ den2,
    const float* __restrict__ h3, const float* __restrict__ b2,
    float* __restrict__ y, int N)
{
    int g = blockIdx.x * 4 + (threadIdx.x >> 6);
    int lane = threadIdx.x & 63;
    if (g >= N) return;
    unsigned k0 = rowstart[g], k1 = rowstart[g + 1];
    float acc = 0.f;
    for (unsigned k = k0; k < k1; ++k) {
        int s = csr_src[k];
        float p = alpha2[k];
        float hv = (lane < 40) ? h3[(size_t)s * 40 + lane] : 0.f;
        acc += p * hv;
    }
    float v = (lane < 40) ? (acc / (den2[g] + EPS_DEN) + b2[lane]) : -INFINITY;
    float mx = v;
#pragma unroll
    for (int off = 32; off; off >>= 1) mx = fmaxf(mx, __shfl_down(mx, off));
    mx = __shfl(mx, 0);
    float ex = (lane < 40) ? expf(v - mx) : 0.f;
    float ss = ex;
#pragma unroll
    for (int off = 32; off; off >>= 1) ss += __shfl_down(ss, off);
    ss = __shfl(ss, 0);
    if (lane < 40) y[(size_t)g * 40 + lane] = v - mx - logf(ss);
}

// ---------- launch ----------
extern "C" void kernel_launch(void* const* d_in, const int* in_sizes, int n_in,
                              void* d_out, int out_size, void* d_ws, size_t ws_size,
                              hipStream_t stream)
{
    const float* x        = (const float*)d_in[0];
    const int*   ei       = (const int*)d_in[1];
    const float* W1       = (const float*)d_in[2];
    const float* att_src1 = (const float*)d_in[3];
    const float* att_dst1 = (const float*)d_in[4];
    const float* b1       = (const float*)d_in[5];
    const float* W2       = (const float*)d_in[6];
    const float* att_src2 = (const float*)d_in[7];
    const float* att_dst2 = (const float*)d_in[8];
    const float* b2       = (const float*)d_in[9];
    float* y = (float*)d_out;

    int N = in_sizes[0] / 512;
    int E = in_sizes[1] / 2;
    int Etot = E + N;
    int nb = (N + 255) / 256;

    char* p = (char*)d_ws;
    float* h1       = (float*)p;   p += (size_t)N * 64 * 4;
    float* a_src1a  = (float*)p;   p += (size_t)N * 8 * 4;
    float* a_dst1a  = (float*)p;   p += (size_t)N * 8 * 4;
    float* h2       = (float*)p;   p += (size_t)N * 64 * 4;
    float* h3       = (float*)p;   p += (size_t)N * 40 * 4;
    float* a_src2a  = (float*)p;   p += (size_t)N * 4;
    float* a_dst2a  = (float*)p;   p += (size_t)N * 4;
    float* m1       = (float*)p;   p += (size_t)N * 8 * 4;
    float* den1     = (float*)p;   p += (size_t)N * 8 * 4;
    float* den2     = (float*)p;   p += (size_t)N * 4;
    float* alpha2   = (float*)p;   p += (size_t)Etot * 4;
    unsigned* deg   = (unsigned*)p; p += (size_t)N * 4;
    unsigned* loc   = (unsigned*)p; p += (size_t)N * 4;
    unsigned* bsum  = (unsigned*)p; p += (size_t)nb * 4;
    unsigned* rowstart = (unsigned*)p; p += (size_t)(N + 1) * 4;
    unsigned* cursor   = (unsigned*)p; p += (size_t)N * 4;
    int* csr_src    = (int*)p;     p += (size_t)Etot * 4;

    hipMemsetAsync(deg, 0, (size_t)N * 4, stream);

    // GEMM1 (MFMA) then attention logits
    gemm1_mfma<<<(N + 127) / 128, 256, 0, stream>>>(x, W1, h1, N);
    att1_kernel<<<(N * 8 + 255) / 256, 256, 0, stream>>>(h1, att_src1, att_dst1, a_src1a, a_dst1a, N);

    // CSR build (shared by both layers)
    deg_kernel<<<(Etot + 255) / 256, 256, 0, stream>>>(ei, deg, E, Etot);
    scanA_kernel<<<nb, 256, 0, stream>>>(deg, loc, bsum, N);
    scanB_kernel<<<1, 1024, 0, stream>>>(bsum, nb);
    scanC_kernel<<<nb, 256, 0, stream>>>(loc, bsum, rowstart, cursor, N, Etot);
    scatter_kernel<<<(Etot + 255) / 256, 256, 0, stream>>>(ei, cursor, csr_src, E, Etot);

    // L1: softmax scalars, then aggregate + bias + relu
    mden1_kernel<<<(N * 8 + 255) / 256, 256, 0, stream>>>(rowstart, csr_src, a_src1a, a_dst1a, m1, den1, N);
    aggr1_kernel<<<(N + 3) / 4, 256, 0, stream>>>(rowstart, csr_src, a_src1a, a_dst1a, m1, den1, h1, b1, h2, N);

    // GEMM2 + attention logits
    gemm2_kernel<<<(N + 3) / 4, 256, 0, stream>>>(h2, W2, att_src2, att_dst2, h3, a_src2a, a_dst2a, N);

    // L2: alpha precompute, then aggregate + bias + log_softmax
    alpha2_kernel<<<(N + 255) / 256, 256, 0, stream>>>(rowstart, csr_src, a_src2a, a_dst2a, alpha2, den2, N);
    aggr2_kernel<<<(N + 3) / 4, 256, 0, stream>>>(rowstart, csr_src, alpha2, den2, h3, b2, y, N);
}

// Round 5
// 902.227 us; speedup vs baseline: 1.1141x; 1.1141x over previous
//
#include <hip/hip_runtime.h>
#include <math.h>

#define NEG_SLOPE 0.2f
#define EPS_DEN 1e-16f

__device__ __forceinline__ float leaky(float v) { return v > 0.f ? v : NEG_SLOPE * v; }

typedef __attribute__((ext_vector_type(8))) short bf16x8;
typedef __attribute__((ext_vector_type(4))) float f32x4;

__device__ __forceinline__ unsigned bf16rne(float f) {
    unsigned u = __float_as_uint(f);
    return (u + 0x7FFFu + ((u >> 16) & 1u)) >> 16;
}
__device__ __forceinline__ unsigned pack2(float a, float b) {
    return bf16rne(a) | (bf16rne(b) << 16);
}
__device__ __forceinline__ float bfu(unsigned short u) {
    return __uint_as_float(((unsigned)u) << 16);
}

// ---------- GEMM1 (MFMA): h1b[N,64](bf16) = x[N,512] @ W1[512,64] ----------
__global__ __launch_bounds__(256) void gemm1_mfma(
    const float* __restrict__ x, const float* __restrict__ W1,
    unsigned short* __restrict__ h1b, int N)
{
    __shared__ __align__(16) unsigned short As[128 * 40];
    __shared__ __align__(16) unsigned short Bs[64 * 40];

    const int t = threadIdx.x;
    const int w = t >> 6;
    const int lane = t & 63;
    const int m16 = lane & 15;
    const int quad = lane >> 4;
    const int rowBase = blockIdx.x * 128;

    f32x4 acc[2][4];
#pragma unroll
    for (int i = 0; i < 2; ++i)
#pragma unroll
        for (int j = 0; j < 4; ++j) acc[i][j] = (f32x4){0.f, 0.f, 0.f, 0.f};

    const float4* x4 = (const float4*)x;

#pragma unroll 1
    for (int chunk = 0; chunk < 16; ++chunk) {
        const int k0 = chunk * 32;
#pragma unroll
        for (int r = 0; r < 4; ++r) {
            int e = t + r * 256;
            int row = e >> 3;
            int kg = e & 7;
            int grow = rowBase + row;
            float4 v = make_float4(0.f, 0.f, 0.f, 0.f);
            if (grow < N) v = x4[(size_t)grow * 128 + (k0 >> 2) + kg];
            uint2 pk = make_uint2(pack2(v.x, v.y), pack2(v.z, v.w));
            *(uint2*)&As[row * 40 + kg * 4] = pk;
        }
        {
            int c = lane;
            int jb = w * 8;
            float f[8];
#pragma unroll
            for (int j = 0; j < 8; ++j) f[j] = W1[(size_t)(k0 + jb + j) * 64 + c];
            uint4 pk;
            pk.x = pack2(f[0], f[1]); pk.y = pack2(f[2], f[3]);
            pk.z = pack2(f[4], f[5]); pk.w = pack2(f[6], f[7]);
            *(uint4*)&Bs[c * 40 + jb] = pk;
        }
        __syncthreads();
        bf16x8 a0 = *(const bf16x8*)&As[(w * 32 + m16) * 40 + quad * 8];
        bf16x8 a1 = *(const bf16x8*)&As[(w * 32 + 16 + m16) * 40 + quad * 8];
#pragma unroll
        for (int j = 0; j < 4; ++j) {
            bf16x8 b = *(const bf16x8*)&Bs[(j * 16 + m16) * 40 + quad * 8];
            acc[0][j] = __builtin_amdgcn_mfma_f32_16x16x32_bf16(a0, b, acc[0][j], 0, 0, 0);
            acc[1][j] = __builtin_amdgcn_mfma_f32_16x16x32_bf16(a1, b, acc[1][j], 0, 0, 0);
        }
        __syncthreads();
    }

#pragma unroll
    for (int i = 0; i < 2; ++i)
#pragma unroll
        for (int reg = 0; reg < 4; ++reg) {
            int r = rowBase + w * 32 + i * 16 + quad * 4 + reg;
            if (r < N) {
#pragma unroll
                for (int j = 0; j < 4; ++j)
                    h1b[(size_t)r * 64 + j * 16 + m16] = (unsigned short)bf16rne(acc[i][j][reg]);
            }
        }
}

// ---------- attention dots for L1 (reads bf16 h1) ----------
__global__ __launch_bounds__(256) void att1_kernel(
    const unsigned short* __restrict__ h1b, const float* __restrict__ att_src,
    const float* __restrict__ att_dst, float* __restrict__ a_src,
    float* __restrict__ a_dst, int N)
{
    int g = blockIdx.x * 256 + threadIdx.x;
    int row = g >> 3, h = g & 7;
    if (row >= N) return;
    uint4 pk = *(const uint4*)(h1b + (size_t)row * 64 + h * 8);
    float v[8];
    v[0] = __uint_as_float(pk.x << 16); v[1] = __uint_as_float(pk.x & 0xFFFF0000u);
    v[2] = __uint_as_float(pk.y << 16); v[3] = __uint_as_float(pk.y & 0xFFFF0000u);
    v[4] = __uint_as_float(pk.z << 16); v[5] = __uint_as_float(pk.z & 0xFFFF0000u);
    v[6] = __uint_as_float(pk.w << 16); v[7] = __uint_as_float(pk.w & 0xFFFF0000u);
    float ps = 0.f, pd = 0.f;
#pragma unroll
    for (int c = 0; c < 8; ++c) {
        ps += v[c] * att_src[h * 8 + c];
        pd += v[c] * att_dst[h * 8 + c];
    }
    a_src[(size_t)row * 8 + h] = ps;
    a_dst[(size_t)row * 8 + h] = pd;
}

// ---------- CSR build ----------
__global__ __launch_bounds__(256) void deg_kernel(
    const int* __restrict__ ei, unsigned* __restrict__ deg, int E, int Etot)
{
    int idx = blockIdx.x * blockDim.x + threadIdx.x;
    if (idx >= Etot) return;
    int d = (idx < E) ? ei[E + idx] : (idx - E);
    atomicAdd(&deg[d], 1u);
}

__global__ __launch_bounds__(256) void scanA_kernel(
    const unsigned* __restrict__ deg, unsigned* __restrict__ loc,
    unsigned* __restrict__ bsum, int N)
{
    __shared__ unsigned sh[256];
    int i = blockIdx.x * 256 + threadIdx.x;
    unsigned v = (i < N) ? deg[i] : 0u;
    sh[threadIdx.x] = v;
    __syncthreads();
    for (int off = 1; off < 256; off <<= 1) {
        unsigned u = (threadIdx.x >= (unsigned)off) ? sh[threadIdx.x - off] : 0u;
        __syncthreads();
        sh[threadIdx.x] += u;
        __syncthreads();
    }
    if (i < N) loc[i] = sh[threadIdx.x] - v;
    if (threadIdx.x == 255) bsum[blockIdx.x] = sh[255];
}

__global__ __launch_bounds__(1024) void scanB_kernel(unsigned* __restrict__ bsum, int nb)
{
    __shared__ unsigned sh[1024];
    int t = threadIdx.x;
    unsigned carry = 0;
    for (int base = 0; base < nb; base += 1024) {
        int i = base + t;
        unsigned v = (i < nb) ? bsum[i] : 0u;
        sh[t] = v;
        __syncthreads();
        for (int off = 1; off < 1024; off <<= 1) {
            unsigned u = (t >= off) ? sh[t - off] : 0u;
            __syncthreads();
            sh[t] += u;
            __syncthreads();
        }
        unsigned incl = sh[t];
        unsigned tot  = sh[1023];
        __syncthreads();
        if (i < nb) bsum[i] = incl - v + carry;
        carry += tot;
        __syncthreads();
    }
}

__global__ __launch_bounds__(256) void scanC_kernel(
    const unsigned* __restrict__ loc, const unsigned* __restrict__ bsum,
    unsigned* __restrict__ rowstart, unsigned* __restrict__ cursor, int N, int Etot)
{
    int i = blockIdx.x * 256 + threadIdx.x;
    if (i >= N) return;
    unsigned r = loc[i] + bsum[blockIdx.x];
    rowstart[i] = r;
    cursor[i] = r;
    if (i == 0) rowstart[N] = (unsigned)Etot;
}

__global__ __launch_bounds__(256) void scatter_kernel(
    const int* __restrict__ ei, unsigned* __restrict__ cursor,
    int* __restrict__ csr_src, int E, int Etot)
{
    int idx = blockIdx.x * blockDim.x + threadIdx.x;
    if (idx >= Etot) return;
    int s, d;
    if (idx < E) { s = ei[idx]; d = ei[E + idx]; } else { s = d = idx - E; }
    unsigned pos = atomicAdd(&cursor[d], 1u);
    csr_src[pos] = s;
}

// ---------- L1 softmax scalars + unnormalized weights: thread per (dst, head) ----------
__global__ __launch_bounds__(256) void mden1_kernel(
    const unsigned* __restrict__ rowstart, const int* __restrict__ csr_src,
    const float* __restrict__ a_src, const float* __restrict__ a_dst,
    float* __restrict__ alpha1, float* __restrict__ den1, int N)
{
    int g = blockIdx.x * 256 + threadIdx.x;
    int dst = g >> 3, h = g & 7;
    if (dst >= N) return;
    float ad = a_dst[(size_t)dst * 8 + h];
    unsigned k0 = rowstart[dst], k1 = rowstart[dst + 1];
    float m = -INFINITY;
    for (unsigned k = k0; k < k1; ++k) {
        int s = csr_src[k];
        m = fmaxf(m, leaky(a_src[(size_t)s * 8 + h] + ad));
    }
    float den = 0.f;
    for (unsigned k = k0; k < k1; ++k) {
        int s = csr_src[k];
        float p = expf(leaky(a_src[(size_t)s * 8 + h] + ad) - m);
        alpha1[(size_t)k * 8 + h] = p;
        den += p;
    }
    den1[(size_t)dst * 8 + h] = den;
}

// ---------- L1 aggregate: wave per dst, pure load·fma ----------
__global__ __launch_bounds__(256) void aggr1_kernel(
    const unsigned* __restrict__ rowstart, const int* __restrict__ csr_src,
    const float* __restrict__ alpha1, const float* __restrict__ den1,
    const unsigned short* __restrict__ h1b, const float* __restrict__ b1,
    float* __restrict__ h2, int N)
{
    int g = blockIdx.x * 4 + (threadIdx.x >> 6);
    int lane = threadIdx.x & 63;
    if (g >= N) return;
    int h = lane >> 3;
    unsigned k0 = rowstart[g], k1 = rowstart[g + 1];
    float acc0 = 0.f, acc1 = 0.f;
    unsigned k = k0;
    for (; k + 2 <= k1; k += 2) {
        int s0 = csr_src[k], s1 = csr_src[k + 1];
        float p0 = alpha1[(size_t)k * 8 + h];
        float p1 = alpha1[(size_t)(k + 1) * 8 + h];
        acc0 += p0 * bfu(h1b[(size_t)s0 * 64 + lane]);
        acc1 += p1 * bfu(h1b[(size_t)s1 * 64 + lane]);
    }
    if (k < k1) {
        int s0 = csr_src[k];
        acc0 += alpha1[(size_t)k * 8 + h] * bfu(h1b[(size_t)s0 * 64 + lane]);
    }
    float v = (acc0 + acc1) / (den1[(size_t)g * 8 + h] + EPS_DEN) + b1[lane];
    h2[(size_t)g * 64 + lane] = v > 0.f ? v : 0.f;
}

// ---------- GEMM2 + attention dots: h3b[N,40](bf16) ----------
__global__ __launch_bounds__(256) void gemm2_kernel(
    const float* __restrict__ h2, const float* __restrict__ W2,
    const float* __restrict__ att_src2, const float* __restrict__ att_dst2,
    unsigned short* __restrict__ h3b, float* __restrict__ a_src, float* __restrict__ a_dst, int N)
{
    __shared__ float Wl[64 * 40];
    int t = threadIdx.x;
    for (int i = t; i < 64 * 40; i += 256) Wl[i] = W2[i];
    __syncthreads();
    int lane = t & 63, wy = t >> 6;
    int row = blockIdx.x * 4 + wy;
    if (row >= N) return;
    float acc = 0.f;
    const float* hr = h2 + (size_t)row * 64;
    if (lane < 40) {
#pragma unroll 8
        for (int k = 0; k < 64; ++k) acc += hr[k] * Wl[k * 40 + lane];
        h3b[(size_t)row * 40 + lane] = (unsigned short)bf16rne(acc);
    }
    float ps = (lane < 40) ? acc * att_src2[lane] : 0.f;
    float pd = (lane < 40) ? acc * att_dst2[lane] : 0.f;
#pragma unroll
    for (int off = 32; off; off >>= 1) { ps += __shfl_down(ps, off); pd += __shfl_down(pd, off); }
    if (lane == 0) { a_src[row] = ps; a_dst[row] = pd; }
}

// ---------- L2 alpha: 8 lanes per dst, coalesced csr walk ----------
__global__ __launch_bounds__(256) void alpha2_kernel(
    const unsigned* __restrict__ rowstart, const int* __restrict__ csr_src,
    const float* __restrict__ a_src, const float* __restrict__ a_dst,
    float* __restrict__ alpha2, float* __restrict__ den2, int N)
{
    int tid = blockIdx.x * 256 + threadIdx.x;
    int dst = tid >> 3, i = tid & 7;
    if (dst >= N) return;
    float ad = a_dst[dst];
    unsigned k0 = rowstart[dst], k1 = rowstart[dst + 1];
    float m = -INFINITY;
    for (unsigned k = k0 + i; k < k1; k += 8)
        m = fmaxf(m, leaky(a_src[csr_src[k]] + ad));
#pragma unroll
    for (int off = 1; off < 8; off <<= 1) m = fmaxf(m, __shfl_xor(m, off));
    float den = 0.f;
    for (unsigned k = k0 + i; k < k1; k += 8) {
        float p = expf(leaky(a_src[csr_src[k]] + ad) - m);
        alpha2[k] = p;
        den += p;
    }
#pragma unroll
    for (int off = 1; off < 8; off <<= 1) den += __shfl_xor(den, off);
    if (i == 0) den2[dst] = den;
}

// ---------- L2 aggregate: wave per dst, fused bias+log_softmax ----------
__global__ __launch_bounds__(256) void aggr2_kernel(
    const unsigned* __restrict__ rowstart, const int* __restrict__ csr_src,
    const float* __restrict__ alpha2, const float* __restrict__ den2,
    const unsigned short* __restrict__ h3b, const float* __restrict__ b2,
    float* __restrict__ y, int N)
{
    int g = blockIdx.x * 4 + (threadIdx.x >> 6);
    int lane = threadIdx.x & 63;
    if (g >= N) return;
    unsigned k0 = rowstart[g], k1 = rowstart[g + 1];
    float acc0 = 0.f, acc1 = 0.f;
    unsigned k = k0;
    for (; k + 2 <= k1; k += 2) {
        int s0 = csr_src[k], s1 = csr_src[k + 1];
        float p0 = alpha2[k], p1 = alpha2[k + 1];
        float hv0 = (lane < 40) ? bfu(h3b[(size_t)s0 * 40 + lane]) : 0.f;
        float hv1 = (lane < 40) ? bfu(h3b[(size_t)s1 * 40 + lane]) : 0.f;
        acc0 += p0 * hv0;
        acc1 += p1 * hv1;
    }
    if (k < k1) {
        int s0 = csr_src[k];
        float hv0 = (lane < 40) ? bfu(h3b[(size_t)s0 * 40 + lane]) : 0.f;
        acc0 += alpha2[k] * hv0;
    }
    float acc = acc0 + acc1;
    float v = (lane < 40) ? (acc / (den2[g] + EPS_DEN) + b2[lane]) : -INFINITY;
    float mx = v;
#pragma unroll
    for (int off = 32; off; off >>= 1) mx = fmaxf(mx, __shfl_down(mx, off));
    mx = __shfl(mx, 0);
    float ex = (lane < 40) ? expf(v - mx) : 0.f;
    float ss = ex;
#pragma unroll
    for (int off = 32; off; off >>= 1) ss += __shfl_down(ss, off);
    ss = __shfl(ss, 0);
    if (lane < 40) y[(size_t)g * 40 + lane] = v - mx - logf(ss);
}

// ---------- launch ----------
extern "C" void kernel_launch(void* const* d_in, const int* in_sizes, int n_in,
                              void* d_out, int out_size, void* d_ws, size_t ws_size,
                              hipStream_t stream)
{
    const float* x        = (const float*)d_in[0];
    const int*   ei       = (const int*)d_in[1];
    const float* W1       = (const float*)d_in[2];
    const float* att_src1 = (const float*)d_in[3];
    const float* att_dst1 = (const float*)d_in[4];
    const float* b1       = (const float*)d_in[5];
    const float* W2       = (const float*)d_in[6];
    const float* att_src2 = (const float*)d_in[7];
    const float* att_dst2 = (const float*)d_in[8];
    const float* b2       = (const float*)d_in[9];
    float* y = (float*)d_out;

    int N = in_sizes[0] / 512;
    int E = in_sizes[1] / 2;
    int Etot = E + N;
    int nb = (N + 255) / 256;

    char* p = (char*)d_ws;
    unsigned short* h1b = (unsigned short*)p; p += (size_t)N * 64 * 2;
    float* a_src1a  = (float*)p;   p += (size_t)N * 8 * 4;
    float* a_dst1a  = (float*)p;   p += (size_t)N * 8 * 4;
    float* h2       = (float*)p;   p += (size_t)N * 64 * 4;
    unsigned short* h3b = (unsigned short*)p; p += (size_t)N * 40 * 2;
    float* a_src2a  = (float*)p;   p += (size_t)N * 4;
    float* a_dst2a  = (float*)p;   p += (size_t)N * 4;
    float* den1     = (float*)p;   p += (size_t)N * 8 * 4;
    float* den2     = (float*)p;   p += (size_t)N * 4;
    float* alpha1   = (float*)p;   p += (size_t)Etot * 8 * 4;
    float* alpha2   = (float*)p;   p += (size_t)Etot * 4;
    unsigned* deg   = (unsigned*)p; p += (size_t)N * 4;
    unsigned* loc   = (unsigned*)p; p += (size_t)N * 4;
    unsigned* bsum  = (unsigned*)p; p += (size_t)nb * 4;
    unsigned* rowstart = (unsigned*)p; p += (size_t)(N + 1) * 4;
    unsigned* cursor   = (unsigned*)p; p += (size_t)N * 4;
    int* csr_src    = (int*)p;     p += (size_t)Etot * 4;

    hipMemsetAsync(deg, 0, (size_t)N * 4, stream);

    // GEMM1 (MFMA) then attention logits
    gemm1_mfma<<<(N + 127) / 128, 256, 0, stream>>>(x, W1, h1b, N);
    att1_kernel<<<(N * 8 + 255) / 256, 256, 0, stream>>>(h1b, att_src1, att_dst1, a_src1a, a_dst1a, N);

    // CSR build (shared by both layers)
    deg_kernel<<<(Etot + 255) / 256, 256, 0, stream>>>(ei, deg, E, Etot);
    scanA_kernel<<<nb, 256, 0, stream>>>(deg, loc, bsum, N);
    scanB_kernel<<<1, 1024, 0, stream>>>(bsum, nb);
    scanC_kernel<<<nb, 256, 0, stream>>>(loc, bsum, rowstart, cursor, N, Etot);
    scatter_kernel<<<(Etot + 255) / 256, 256, 0, stream>>>(ei, cursor, csr_src, E, Etot);

    // L1: softmax scalars + weights, then pure-fma aggregate + bias + relu
    mden1_kernel<<<(N * 8 + 255) / 256, 256, 0, stream>>>(rowstart, csr_src, a_src1a, a_dst1a, alpha1, den1, N);
    aggr1_kernel<<<(N + 3) / 4, 256, 0, stream>>>(rowstart, csr_src, alpha1, den1, h1b, b1, h2, N);

    // GEMM2 + attention logits
    gemm2_kernel<<<(N + 3) / 4, 256, 0, stream>>>(h2, W2, att_src2, att_dst2, h3b, a_src2a, a_dst2a, N);

    // L2: alpha precompute, then aggregate + bias + log_softmax
    alpha2_kernel<<<(N * 8 + 255) / 256, 256, 0, stream>>>(rowstart, csr_src, a_src2a, a_dst2a, alpha2, den2, N);
    aggr2_kernel<<<(N + 3) / 4, 256, 0, stream>>>(rowstart, csr_src, alpha2, den2, h3b, b2, y, N);
}